// Round 3
// baseline (357.974 us; speedup 1.0000x reference)
//
#include <hip/hip_runtime.h>

// Tree_53824530153725 on MI355X.
// Key insight: feature_mask is one-hot => feats = gather(x, idx). Tree output
// in heap layout: out[t] = out[t>>1] * (t&1 ? 1-s[t>>1] : s[t>>1]), s[n] =
// sigmoid(x[row, idx[n]]). Memory-bound: ~330 MB HBM traffic -> ~55-65 us tree floor.
//
// R1: extract_idx was 4 blocks x 1024 serialized HBM-latency loads (~322 us).
// Replaced with coalesced full-matrix scan (~5 us theoretical).
// R2: WRITE_SIZE 441 MB vs 256 MB ideal: strided NT partial-line stores for
// L9/L10. Fixed by staging in LDS, writing lane-contiguous v4f. 443->350 us.
// R3: tree ~80 us vs ~60 floor. Remove both __syncthreads (all LDS traffic is
// intra-wave: each wave owns lds[wid]; wave64 lockstep + waitcnt is enough),
// use global_load_lds (16B) for x staging (no VGPR roundtrip, x allocates in
// cache again -> lower FETCH next iter), issue idx loads before x-wait.

static constexpr int FEAT  = 1024;
static constexpr int NLEAF = 1024;
static constexpr int OUTW  = 2048;

// Native clang vector types: __builtin_nontemporal_* rejects HIP_vector_type.
typedef float v2f __attribute__((ext_vector_type(2)));
typedef float v4f __attribute__((ext_vector_type(4)));

// fm is (FEAT=1024 rows, NLEAF=1024 cols), exactly one 1.0 per column.
// Coalesced scan of all 1M entries; where fm[row][col] > 0.5, idx[col] = row.
// Every column written exactly once => poisoned d_ws fully overwritten.
__global__ __launch_bounds__(256) void extract_idx_kernel(
        const float* __restrict__ fm, int* __restrict__ idx) {
    int e = (blockIdx.x * 256 + threadIdx.x) * 4;     // element index in [0, 1M)
    v4f v = __builtin_nontemporal_load(reinterpret_cast<const v4f*>(fm + e));
    int row = e >> 10;                                // e / NLEAF
    int col = e & (NLEAF - 1);                        // e % NLEAF (col+3 <= 1023)
    if (v.x > 0.5f) idx[col]     = row;
    if (v.y > 0.5f) idx[col + 1] = row;
    if (v.z > 0.5f) idx[col + 2] = row;
    if (v.w > 0.5f) idx[col + 3] = row;
}

__device__ __forceinline__ float sig(float v) {
    // 1/(1+e^-v) via v_exp_f32 + v_rcp_f32; plenty for absmax 2e-2 threshold.
    return __builtin_amdgcn_rcpf(1.0f + __expf(-v));
}

// One wave (64 lanes) per batch row; 4 waves per block, fully independent
// (no block barriers: each wave only touches lds[wid]).
// LDS 6 KB/wave = union{ x row (4 KB) ; L9+L10 staging (6 KB) }.
// Tree lives in registers:
//   levels 1..5 : shuffle cascade, heap-index == lane  (out[0..63])
//   level  6    : shuffle from level-5 regs            (out[64..127])
//   levels 7..10: lane-local subtree under node 64+lane
// Levels 1..8 store direct (lane-contiguous per instruction); levels 9..10
// stage in LDS then store lane-contiguous v4f (full 64B lines).
__global__ __launch_bounds__(256) void tree_kernel(
        const float* __restrict__ x, const int* __restrict__ idx,
        float* __restrict__ out) {
    __shared__ float lds[4][1536];       // 24 KB/block
    const int wid  = threadIdx.x >> 6;
    const int lane = threadIdx.x & 63;
    const int row  = (blockIdx.x << 2) | wid;

    const float* __restrict__ xr = x + (size_t)row * FEAT;
    float* __restrict__ orow = out + (size_t)row * OUTW;
    float* lx = lds[wid];

    // ---- issue x row staging direct-to-LDS (16B/lane, wave-uniform base +
    // lane*16 dest = exactly our layout). Counted by vmcnt.
#pragma unroll
    for (int i = 0; i < 4; ++i) {
        __builtin_amdgcn_global_load_lds(
            (const __attribute__((address_space(1))) void*)(xr + 256 * i + 4 * lane),
            (__attribute__((address_space(3))) void*)(lx + 256 * i),
            16, 0, 0);
    }

    // ---- idx loads overlap the x-load latency (L1/L2-hot, same for all rows)
    int  iA  = idx[lane];                                               // s[lane]
    int  iB  = idx[64 + lane];                                          // s[64+l]
    int2 iC  = *reinterpret_cast<const int2*>(idx + 128 + 2 * lane);    // s[128+2l..]
    int4 iD  = *reinterpret_cast<const int4*>(idx + 256 + 4 * lane);    // s[256+4l..]
    int4 iE0 = *reinterpret_cast<const int4*>(idx + 512 + 8 * lane);    // s[512+8l..]
    int4 iE1 = *reinterpret_cast<const int4*>(idx + 516 + 8 * lane);

    // Drain x->LDS (and idx) before gathering. Compiler can't see the
    // global_load_lds -> ds_read dependence: explicit wait + sched fence.
    asm volatile("s_waitcnt vmcnt(0)" ::: "memory");
    __builtin_amdgcn_sched_barrier(0);

    float s_heap = sig(lx[iA]);          // lane 0's value is never consumed
    float sB  = sig(lx[iB]);
    float sC0 = sig(lx[iC.x]), sC1 = sig(lx[iC.y]);
    float sD0 = sig(lx[iD.x]), sD1 = sig(lx[iD.y]);
    float sD2 = sig(lx[iD.z]), sD3 = sig(lx[iD.w]);
    float sE0 = sig(lx[iE0.x]), sE1 = sig(lx[iE0.y]);
    float sE2 = sig(lx[iE0.z]), sE3 = sig(lx[iE0.w]);
    float sE4 = sig(lx[iE1.x]), sE5 = sig(lx[iE1.y]);
    float sE6 = sig(lx[iE1.z]), sE7 = sig(lx[iE1.w]);
    // x region of LDS is dead from here on; reused as L9/L10 staging below.

    // ---- levels 1..5: heap index == lane; lanes 0,1 stay 1.0 (the ones piece)
    float m_heap = 1.0f;
#pragma unroll
    for (int L = 1; L <= 5; ++L) {
        float parent = __shfl(m_heap, lane >> 1, 64);
        float sp     = __shfl(s_heap, lane >> 1, 64);
        float val    = parent * ((lane & 1) ? (1.0f - sp) : sp);
        bool active  = (lane >= (1 << L)) && (lane < (2 << L));
        m_heap = active ? val : m_heap;
    }
    __builtin_nontemporal_store(m_heap, orow + lane);          // out[0..63]

    // ---- level 6: M[64+lane] ----
    float p6 = __shfl(m_heap, 32 + (lane >> 1), 64);
    float s6 = __shfl(s_heap, 32 + (lane >> 1), 64);
    float m6 = p6 * ((lane & 1) ? (1.0f - s6) : s6);
    __builtin_nontemporal_store(m6, orow + 64 + lane);         // out[64..127]

    // ---- level 7: children of node 64+lane ----
    v2f v7;
    v7.x = m6 * sB;
    v7.y = m6 * (1.0f - sB);
    __builtin_nontemporal_store(v7, reinterpret_cast<v2f*>(orow + 128 + 2 * lane));

    // ---- level 8: children of nodes 128+2l, 129+2l ----
    v4f v8;
    v8.x = v7.x * sC0; v8.y = v7.x * (1.0f - sC0);
    v8.z = v7.y * sC1; v8.w = v7.y * (1.0f - sC1);
    __builtin_nontemporal_store(v8, reinterpret_cast<v4f*>(orow + 256 + 4 * lane));

    // ---- level 9: children of nodes 256+4l+j -> stage at lds floats [0,512) ----
    float m9[8];
    m9[0] = v8.x * sD0; m9[1] = v8.x * (1.0f - sD0);
    m9[2] = v8.y * sD1; m9[3] = v8.y * (1.0f - sD1);
    m9[4] = v8.z * sD2; m9[5] = v8.z * (1.0f - sD2);
    m9[6] = v8.w * sD3; m9[7] = v8.w * (1.0f - sD3);
    v4f* st9 = reinterpret_cast<v4f*>(lx) + 2 * lane;          // float off 8*lane
    v4f t;
    t.x = m9[0]; t.y = m9[1]; t.z = m9[2]; t.w = m9[3];
    st9[0] = t;
    t.x = m9[4]; t.y = m9[5]; t.z = m9[6]; t.w = m9[7];
    st9[1] = t;

    // ---- level 10: children of nodes 512+8l+j -> stage at lds floats [512,1536) ----
    v4f* st10 = reinterpret_cast<v4f*>(lx + 512) + 4 * lane;   // float off 512+16*lane
    v4f u;
    u.x = m9[0] * sE0; u.y = m9[0] * (1.0f - sE0);
    u.z = m9[1] * sE1; u.w = m9[1] * (1.0f - sE1);
    st10[0] = u;
    u.x = m9[2] * sE2; u.y = m9[2] * (1.0f - sE2);
    u.z = m9[3] * sE3; u.w = m9[3] * (1.0f - sE3);
    st10[1] = u;
    u.x = m9[4] * sE4; u.y = m9[4] * (1.0f - sE4);
    u.z = m9[5] * sE5; u.w = m9[5] * (1.0f - sE5);
    st10[2] = u;
    u.x = m9[6] * sE6; u.y = m9[6] * (1.0f - sE6);
    u.z = m9[7] * sE7; u.w = m9[7] * (1.0f - sE7);
    st10[3] = u;

    // ---- intra-wave visibility: wave64 lockstep + LDS drain (no block barrier;
    // each wave only reads its own lds[wid] region).
    asm volatile("s_waitcnt lgkmcnt(0)" ::: "memory");
    __builtin_amdgcn_sched_barrier(0);

    // Write out lane-contiguous: each v4f NT store covers 1 KiB of full lines.
    const v4f* lo4 = reinterpret_cast<const v4f*>(lx);
    v4f* o9g  = reinterpret_cast<v4f*>(orow + 512);            // 128 v4f
    v4f* o10g = reinterpret_cast<v4f*>(orow + 1024);           // 256 v4f
#pragma unroll
    for (int j = 0; j < 2; ++j)
        __builtin_nontemporal_store(lo4[lane + 64 * j], o9g + lane + 64 * j);
#pragma unroll
    for (int j = 0; j < 4; ++j)
        __builtin_nontemporal_store(lo4[128 + lane + 64 * j], o10g + lane + 64 * j);
}

extern "C" void kernel_launch(void* const* d_in, const int* in_sizes, int n_in,
                              void* d_out, int out_size, void* d_ws, size_t ws_size,
                              hipStream_t stream) {
    const float* x  = (const float*)d_in[0];   // (32768, 1024) f32
    const float* fm = (const float*)d_in[1];   // (1024, 1024) f32 one-hot cols
    float* out = (float*)d_out;                // (32768, 2048) f32
    int* idx = (int*)d_ws;                     // 1024 ints scratch

    // d_ws is re-poisoned before every call: recompute idx every launch.
    // Full-matrix coalesced scan: 1M elements / (256 thr * 4 elem) = 1024 blocks.
    extract_idx_kernel<<<(FEAT * NLEAF) / (256 * 4), 256, 0, stream>>>(fm, idx);

    int rows = in_sizes[0] / FEAT;             // 32768
    tree_kernel<<<rows / 4, 256, 0, stream>>>(x, idx, out);
}

// Round 4
// 347.932 us; speedup vs baseline: 1.0289x; 1.0289x over previous
//
#include <hip/hip_runtime.h>

// Tree_53824530153725 on MI355X.
// Key insight: feature_mask is one-hot => feats = gather(x, idx). Tree output
// in heap layout: out[t] = out[t>>1] * (t&1 ? 1-s[t>>1] : s[t>>1]), s[n] =
// sigmoid(x[row, idx[n]]). Memory-bound: ~330 MB HBM traffic -> ~55-65 us tree floor.
//
// R1: extract_idx was 4 blocks x 1024 serialized HBM-latency loads (~322 us).
// Replaced with coalesced full-matrix scan (~5 us). 489 -> 443.
// R2: WRITE_SIZE 441 MB vs 256 MB ideal: strided NT partial-line stores for
// L9/L10. Fixed by staging in LDS, writing lane-contiguous v4f. 443 -> 350.
// R3: 3-change experiment (no barriers + global_load_lds + no NT on x) = 358,
// slight regression; the manual vmcnt(0) fence serialized idx+x drain.
// R4: R2 base + the one mechanically-justified piece of R3: drop both block
// barriers (all LDS traffic is wave-private to lds[wid]; DS pipe is in-order
// per wave, compiler tracks the VGPR-staged ds_write->ds_read deps) and hoist
// idx loads ahead of the x-stage so both latencies overlap.

static constexpr int FEAT  = 1024;
static constexpr int NLEAF = 1024;
static constexpr int OUTW  = 2048;

// Native clang vector types: __builtin_nontemporal_* rejects HIP_vector_type.
typedef float v2f __attribute__((ext_vector_type(2)));
typedef float v4f __attribute__((ext_vector_type(4)));

// fm is (FEAT=1024 rows, NLEAF=1024 cols), exactly one 1.0 per column.
// Coalesced scan of all 1M entries; where fm[row][col] > 0.5, idx[col] = row.
// Every column written exactly once => poisoned d_ws fully overwritten.
__global__ __launch_bounds__(256) void extract_idx_kernel(
        const float* __restrict__ fm, int* __restrict__ idx) {
    int e = (blockIdx.x * 256 + threadIdx.x) * 4;     // element index in [0, 1M)
    v4f v = __builtin_nontemporal_load(reinterpret_cast<const v4f*>(fm + e));
    int row = e >> 10;                                // e / NLEAF
    int col = e & (NLEAF - 1);                        // e % NLEAF (col+3 <= 1023)
    if (v.x > 0.5f) idx[col]     = row;
    if (v.y > 0.5f) idx[col + 1] = row;
    if (v.z > 0.5f) idx[col + 2] = row;
    if (v.w > 0.5f) idx[col + 3] = row;
}

__device__ __forceinline__ float sig(float v) {
    // 1/(1+e^-v) via v_exp_f32 + v_rcp_f32; plenty for absmax 2e-2 threshold.
    return __builtin_amdgcn_rcpf(1.0f + __expf(-v));
}

// One wave (64 lanes) per batch row; 4 waves per block, fully independent —
// no block barriers (each wave only touches its own lds[wid] region).
// LDS 6 KB/wave = union{ x row (4 KB) ; L9+L10 staging (6 KB) }.
// Tree lives in registers:
//   levels 1..5 : shuffle cascade, heap-index == lane  (out[0..63])
//   level  6    : shuffle from level-5 regs            (out[64..127])
//   levels 7..10: lane-local subtree under node 64+lane
// Levels 1..8 store direct (lane-contiguous per instruction); levels 9..10
// stage in LDS then store lane-contiguous v4f (full 64B lines).
__global__ __launch_bounds__(256) void tree_kernel(
        const float* __restrict__ x, const int* __restrict__ idx,
        float* __restrict__ out) {
    __shared__ float lds[4][1536];       // 24 KB/block
    const int wid  = threadIdx.x >> 6;
    const int lane = threadIdx.x & 63;
    const int row  = (blockIdx.x << 2) | wid;

    const float* __restrict__ xr = x + (size_t)row * FEAT;
    float* __restrict__ orow = out + (size_t)row * OUTW;
    float* lx = lds[wid];

    // ---- idx loads first: L2-hot latency hides under the x NT-load latency
    int  iA  = idx[lane];                                               // s[lane]
    int  iB  = idx[64 + lane];                                          // s[64+l]
    int2 iC  = *reinterpret_cast<const int2*>(idx + 128 + 2 * lane);    // s[128+2l..]
    int4 iD  = *reinterpret_cast<const int4*>(idx + 256 + 4 * lane);    // s[256+4l..]
    int4 iE0 = *reinterpret_cast<const int4*>(idx + 512 + 8 * lane);    // s[512+8l..]
    int4 iE1 = *reinterpret_cast<const int4*>(idx + 516 + 8 * lane);

    // ---- stage x row to LDS (coalesced 16B, read-once => nontemporal) ----
    const v4f* xr4 = reinterpret_cast<const v4f*>(xr);
#pragma unroll
    for (int i = 0; i < 4; ++i) {
        v4f v = __builtin_nontemporal_load(xr4 + lane + 64 * i);
        reinterpret_cast<v4f*>(lx)[lane + 64 * i] = v;
    }
    // No barrier: each wave reads only what it wrote; DS pipe is in-order
    // per wave and the compiler inserts the lgkmcnt waits for these deps.

    float s_heap = sig(lx[iA]);          // lane 0's value is never consumed
    float sB  = sig(lx[iB]);
    float sC0 = sig(lx[iC.x]), sC1 = sig(lx[iC.y]);
    float sD0 = sig(lx[iD.x]), sD1 = sig(lx[iD.y]);
    float sD2 = sig(lx[iD.z]), sD3 = sig(lx[iD.w]);
    float sE0 = sig(lx[iE0.x]), sE1 = sig(lx[iE0.y]);
    float sE2 = sig(lx[iE0.z]), sE3 = sig(lx[iE0.w]);
    float sE4 = sig(lx[iE1.x]), sE5 = sig(lx[iE1.y]);
    float sE6 = sig(lx[iE1.z]), sE7 = sig(lx[iE1.w]);
    // x region of LDS is dead from here on; reused as L9/L10 staging below.

    // ---- levels 1..5: heap index == lane; lanes 0,1 stay 1.0 (the ones piece)
    float m_heap = 1.0f;
#pragma unroll
    for (int L = 1; L <= 5; ++L) {
        float parent = __shfl(m_heap, lane >> 1, 64);
        float sp     = __shfl(s_heap, lane >> 1, 64);
        float val    = parent * ((lane & 1) ? (1.0f - sp) : sp);
        bool active  = (lane >= (1 << L)) && (lane < (2 << L));
        m_heap = active ? val : m_heap;
    }
    __builtin_nontemporal_store(m_heap, orow + lane);          // out[0..63]

    // ---- level 6: M[64+lane] ----
    float p6 = __shfl(m_heap, 32 + (lane >> 1), 64);
    float s6 = __shfl(s_heap, 32 + (lane >> 1), 64);
    float m6 = p6 * ((lane & 1) ? (1.0f - s6) : s6);
    __builtin_nontemporal_store(m6, orow + 64 + lane);         // out[64..127]

    // ---- level 7: children of node 64+lane ----
    v2f v7;
    v7.x = m6 * sB;
    v7.y = m6 * (1.0f - sB);
    __builtin_nontemporal_store(v7, reinterpret_cast<v2f*>(orow + 128 + 2 * lane));

    // ---- level 8: children of nodes 128+2l, 129+2l ----
    v4f v8;
    v8.x = v7.x * sC0; v8.y = v7.x * (1.0f - sC0);
    v8.z = v7.y * sC1; v8.w = v7.y * (1.0f - sC1);
    __builtin_nontemporal_store(v8, reinterpret_cast<v4f*>(orow + 256 + 4 * lane));

    // ---- level 9: children of nodes 256+4l+j -> stage at lds floats [0,512) ----
    float m9[8];
    m9[0] = v8.x * sD0; m9[1] = v8.x * (1.0f - sD0);
    m9[2] = v8.y * sD1; m9[3] = v8.y * (1.0f - sD1);
    m9[4] = v8.z * sD2; m9[5] = v8.z * (1.0f - sD2);
    m9[6] = v8.w * sD3; m9[7] = v8.w * (1.0f - sD3);
    v4f* st9 = reinterpret_cast<v4f*>(lx) + 2 * lane;          // float off 8*lane
    v4f t;
    t.x = m9[0]; t.y = m9[1]; t.z = m9[2]; t.w = m9[3];
    st9[0] = t;
    t.x = m9[4]; t.y = m9[5]; t.z = m9[6]; t.w = m9[7];
    st9[1] = t;

    // ---- level 10: children of nodes 512+8l+j -> stage at lds floats [512,1536) ----
    v4f* st10 = reinterpret_cast<v4f*>(lx + 512) + 4 * lane;   // float off 512+16*lane
    v4f u;
    u.x = m9[0] * sE0; u.y = m9[0] * (1.0f - sE0);
    u.z = m9[1] * sE1; u.w = m9[1] * (1.0f - sE1);
    st10[0] = u;
    u.x = m9[2] * sE2; u.y = m9[2] * (1.0f - sE2);
    u.z = m9[3] * sE3; u.w = m9[3] * (1.0f - sE3);
    st10[1] = u;
    u.x = m9[4] * sE4; u.y = m9[4] * (1.0f - sE4);
    u.z = m9[5] * sE5; u.w = m9[5] * (1.0f - sE5);
    st10[2] = u;
    u.x = m9[6] * sE6; u.y = m9[6] * (1.0f - sE6);
    u.z = m9[7] * sE7; u.w = m9[7] * (1.0f - sE7);
    st10[3] = u;

    // No barrier: the lane-crossed reads below hit only this wave's region;
    // per-wave DS ordering + compiler lgkmcnt waits give visibility.

    // Write out lane-contiguous: each v4f NT store covers 1 KiB of full lines.
    const v4f* lo4 = reinterpret_cast<const v4f*>(lx);
    v4f* o9g  = reinterpret_cast<v4f*>(orow + 512);            // 128 v4f
    v4f* o10g = reinterpret_cast<v4f*>(orow + 1024);           // 256 v4f
#pragma unroll
    for (int j = 0; j < 2; ++j)
        __builtin_nontemporal_store(lo4[lane + 64 * j], o9g + lane + 64 * j);
#pragma unroll
    for (int j = 0; j < 4; ++j)
        __builtin_nontemporal_store(lo4[128 + lane + 64 * j], o10g + lane + 64 * j);
}

extern "C" void kernel_launch(void* const* d_in, const int* in_sizes, int n_in,
                              void* d_out, int out_size, void* d_ws, size_t ws_size,
                              hipStream_t stream) {
    const float* x  = (const float*)d_in[0];   // (32768, 1024) f32
    const float* fm = (const float*)d_in[1];   // (1024, 1024) f32 one-hot cols
    float* out = (float*)d_out;                // (32768, 2048) f32
    int* idx = (int*)d_ws;                     // 1024 ints scratch

    // d_ws is re-poisoned before every call: recompute idx every launch.
    // Full-matrix coalesced scan: 1M elements / (256 thr * 4 elem) = 1024 blocks.
    extract_idx_kernel<<<(FEAT * NLEAF) / (256 * 4), 256, 0, stream>>>(fm, idx);

    int rows = in_sizes[0] / FEAT;             // 32768
    tree_kernel<<<rows / 4, 256, 0, stream>>>(x, idx, out);
}